// Round 6
// baseline (699.473 us; speedup 1.0000x reference)
//
#include <hip/hip_runtime.h>

// Problem constants (fixed by setup_inputs)
#define B_    4
#define H_    32
#define W_    32
#define N_    1024      // H*W
#define CIN_  256
#define CHID_ 1024
#define C2_   512

typedef __attribute__((ext_vector_type(8))) short short8b;   // 8 bf16
typedef __attribute__((ext_vector_type(4))) float f32x4;     // MFMA acc

// fp32 -> bf16 (RNE)
__device__ __forceinline__ unsigned int f2bf2(float lo, float hi) {
    unsigned int ul = __float_as_uint(lo);
    unsigned int uh = __float_as_uint(hi);
    ul += 0x7fffu + ((ul >> 16) & 1u);
    uh += 0x7fffu + ((uh >> 16) & 1u);
    return (ul >> 16) | (uh & 0xffff0000u);
}
__device__ __forceinline__ unsigned short f2bf(float f) {
    unsigned int u = __float_as_uint(f);
    u += 0x7fffu + ((u >> 16) & 1u);
    return (unsigned short)(u >> 16);
}
// bf16 pair -> f32 (bf16<<16 is the f32 bit pattern)
__device__ __forceinline__ float bflo(unsigned int u) { return __uint_as_float(u << 16); }
__device__ __forceinline__ float bfhi(unsigned int u) { return __uint_as_float(u & 0xffff0000u); }

#define ROWP 40   // LDS row pitch (ushorts): 80B stride -> 2-way alias = free
#define MFMA_(a, b, c) __builtin_amdgcn_mfma_f32_16x16x32_bf16(a, b, c, 0, 0, 0)

template<int X> struct Log2 { static constexpr int v = 1 + Log2<X/2>::v; };
template<> struct Log2<1> { static constexpr int v = 0; };

// Register staging sets (named fields only -> stays in VGPRs, rule #20)
struct ASet { uint4 r0, r1, r2, r3; float4 cw; };
struct BSet { short8b b0, b1, b2, b3; };

// ---------------------------------------------------------------------------
// bf16 MFMA GEMM, tile 64x128, 8 waves (2r x 4c), BK=64.
// 2-phase register pipeline: at step g -> issue raw A loads for g+2 (regs),
// blend/convert the set loaded at g-1 and ds_write it for step g+1, MFMA
// step g from LDS. The vmcnt wait before blend is for loads issued a full
// step earlier -> memory latency off the critical path (1 block/CU).
// B fragment-packed in global, register double-buffered (1 step ahead).
//   AMODE 0: fp32 row-major + cvt   (x for fc1, ytok for fc2); taps=1
//   AMODE 1: bf16 + spatial shift   (hb for offsets, daccb for plain convs)
//   AMODE 2: bf16 + bilinear gather (hb for deform convs)
//   OUTMODE 0: fp32 + bias   1: bf16 + bias   2: fp32 partial slab (z-split)
// Grid: GX>0 -> 1-D grid GX*64, o0=(bid&(GX-1))*128, m0=(bid/GX)*64
//       GX==0 -> (1, 64, Z): o0=0, taps z*tcnt..+tcnt, partial slab z.
// ---------------------------------------------------------------------------
template<int AMODE, int KS, int CH, int OUTMODE, int GX>
__global__ __launch_bounds__(512, 2)
void cgemm(const void* __restrict__ Asrc, int lda,
           const unsigned short* __restrict__ Bp, int nk32,
           int tcnt, int KK,
           const float* __restrict__ bias, void* __restrict__ Cout,
           int ldo, int O, int nO16,
           const short4* __restrict__ cidx, const float4* __restrict__ cwt)
{
    constexpr int CHS = Log2<CH>::v;
    __shared__ unsigned short As[2][2][64 * ROWP];

    const int tid = threadIdx.x;
    int m0, o0, tbeg, zslab;
    if constexpr (GX > 0) {
        const int bid = blockIdx.x;
        o0 = (bid & (GX - 1)) * 128;
        m0 = (bid / GX) * 64;
        tbeg = 0; zslab = 0;
    } else {
        o0 = 0;
        m0 = blockIdx.y * 64;
        zslab = blockIdx.z;
        tbeg = zslab * tcnt;
    }

    // staging role: row = tid>>3 (0..63), k-octet = (tid&7)*8
    const int srow = tid >> 3;
    const int sk8  = (tid & 7) << 3;
    const int am = m0 + srow;
    const int an = am & (N_ - 1), ab = am >> 10;
    const int ay = an >> 5, ax = an & 31;

    // compute role: 8 waves 2x4, wave subtile 32x32
    const int lane = tid & 63, wid = tid >> 6;
    const int wr = (wid >> 2) * 32, wc = (wid & 3) * 32;
    const int l15 = lane & 15, lk = (lane >> 4) * 8;

    const int o16a = min((o0 + wc) >> 4, nO16 - 1);
    const int o16b = min((o0 + wc + 16) >> 4, nO16 - 1);
    const unsigned short* bbA = Bp + (size_t)o16a * nk32 * 512 + lane * 8;
    const unsigned short* bbB = Bp + (size_t)o16b * nk32 * 512 + lane * 8;

    const int T = tcnt << CHS;          // total K64 steps
    const int qbase = (tbeg << CHS) * 2;

    // ---- load-side tap state (shared, consumed immediately by loads) ----
    const float* fp = nullptr;
    const unsigned short* sp = nullptr;
    bool svalid = false;
    const unsigned short *g0p = nullptr, *g1p = nullptr,
                         *g2p = nullptr, *g3p = nullptr;
    float4 curCw = {0.f, 0.f, 0.f, 0.f};
    short4 ciPref = {0, 0, 0, 0};
    float4 cwPref = {0.f, 0.f, 0.f, 0.f};

    if constexpr (AMODE == 0) {
        fp = (const float*)Asrc + (size_t)am * lda + sk8;
    } else if constexpr (AMODE == 2) {
        ciPref = cidx[(size_t)am * KK + tbeg];
        cwPref = cwt [(size_t)am * KK + tbeg];
    }

    auto advanceTap = [&](int tp) {
        if constexpr (AMODE == 1) {
            const int PAD = KS / 2;
            const int ty = tp / KS, tx = tp - ty * KS;
            const int yy = ay + ty - PAD, xx = ax + tx - PAD;
            svalid = (yy >= 0 && yy < H_ && xx >= 0 && xx < W_);
            if (svalid)
                sp = (const unsigned short*)Asrc
                   + (size_t)((ab << 10) | (yy << 5) | xx) * lda + sk8;
        } else if constexpr (AMODE == 2) {
            const unsigned short* base = (const unsigned short*)Asrc;
            g0p = base + (size_t)(int)ciPref.x * lda + sk8;
            g1p = base + (size_t)(int)ciPref.y * lda + sk8;
            g2p = base + (size_t)(int)ciPref.z * lda + sk8;
            g3p = base + (size_t)(int)ciPref.w * lda + sk8;
            curCw = cwPref;
            ciPref = cidx[(size_t)am * KK + tp + 1];   // prefetch next tap
            cwPref = cwt [(size_t)am * KK + tp + 1];
        }
    };

    auto loadRaw = [&](ASet& S, int u) {
        if constexpr (AMODE == 0) {
            S.r0 = *(const uint4*)(fp + (u << 6));
            S.r1 = *(const uint4*)(fp + (u << 6) + 4);
        } else if constexpr (AMODE == 1) {
            S.r0 = svalid ? *(const uint4*)(sp + (u << 6))
                          : make_uint4(0u, 0u, 0u, 0u);
        } else {
            S.r0 = *(const uint4*)(g0p + (u << 6));
            S.r1 = *(const uint4*)(g1p + (u << 6));
            S.r2 = *(const uint4*)(g2p + (u << 6));
            S.r3 = *(const uint4*)(g3p + (u << 6));
            S.cw = curCw;
        }
    };

    auto bl1 = [](unsigned a, unsigned b, unsigned c, unsigned d, float4 cw) {
        const float lo = cw.x * bflo(a) + cw.y * bflo(b)
                       + cw.z * bflo(c) + cw.w * bflo(d);
        const float hi = cw.x * bfhi(a) + cw.y * bfhi(b)
                       + cw.z * bfhi(c) + cw.w * bfhi(d);
        return f2bf2(lo, hi);
    };

    auto blendWrite = [&](ASet& S, int buf) {
        uint4 o;
        if constexpr (AMODE == 0) {
            o = make_uint4(f2bf2(__uint_as_float(S.r0.x), __uint_as_float(S.r0.y)),
                           f2bf2(__uint_as_float(S.r0.z), __uint_as_float(S.r0.w)),
                           f2bf2(__uint_as_float(S.r1.x), __uint_as_float(S.r1.y)),
                           f2bf2(__uint_as_float(S.r1.z), __uint_as_float(S.r1.w)));
        } else if constexpr (AMODE == 1) {
            o = S.r0;
        } else {
            o = make_uint4(bl1(S.r0.x, S.r1.x, S.r2.x, S.r3.x, S.cw),
                           bl1(S.r0.y, S.r1.y, S.r2.y, S.r3.y, S.cw),
                           bl1(S.r0.z, S.r1.z, S.r2.z, S.r3.z, S.cw),
                           bl1(S.r0.w, S.r1.w, S.r2.w, S.r3.w, S.cw));
        }
        *(uint4*)&As[buf][sk8 >> 5][srow * ROWP + (sk8 & 31)] = o;
    };

    auto loadB = [&](BSet& Bv, int g) {
        const int q = qbase + 2 * g;
        Bv.b0 = *(const short8b*)(bbA + (size_t)q * 512);
        Bv.b1 = *(const short8b*)(bbA + (size_t)(q + 1) * 512);
        Bv.b2 = *(const short8b*)(bbB + (size_t)q * 512);
        Bv.b3 = *(const short8b*)(bbB + (size_t)(q + 1) * 512);
    };

    f32x4 acc[2][2];
#pragma unroll
    for (int i = 0; i < 2; ++i)
#pragma unroll
        for (int j = 0; j < 2; ++j)
            acc[i][j] = (f32x4){0.f, 0.f, 0.f, 0.f};

    ASet S0, S1; BSet B0, B1;

    // ---- prologue: stage step 0 into As[0]; raw-load step 1; B for step 0 ----
    advanceTap(tbeg);
    {
        ASet P;
        loadRaw(P, 0);
        blendWrite(P, 0);        // waits its own loads (one-time stall)
    }
    loadRaw(S0, 1);              // step 1 is within tap tbeg (CH >= 4)
    loadB(B0, 0);
    __syncthreads();

    int cur = 0;

    auto iter = [&](int g, ASet& N, ASet& F, BSet& bc, BSet& bn) {
        if (g + 1 < T) loadB(bn, g + 1);
        if (g + 2 < T) {
            const int gn = g + 2;
            if ((gn & (CH - 1)) == 0) advanceTap(tbeg + (gn >> CHS));
            loadRaw(F, gn & (CH - 1));
        }
        if (g + 1 < T) blendWrite(N, cur ^ 1);   // N loaded at step g-1

        const unsigned short* a0 = As[cur][0];
        const unsigned short* a1 = As[cur][1];
        const short8b af00 = *(const short8b*)(a0 + (wr      + l15) * ROWP + lk);
        const short8b af01 = *(const short8b*)(a0 + (wr + 16 + l15) * ROWP + lk);
        const short8b af10 = *(const short8b*)(a1 + (wr      + l15) * ROWP + lk);
        const short8b af11 = *(const short8b*)(a1 + (wr + 16 + l15) * ROWP + lk);

        acc[0][0] = MFMA_(af00, bc.b0, acc[0][0]);
        acc[0][1] = MFMA_(af00, bc.b2, acc[0][1]);
        acc[1][0] = MFMA_(af01, bc.b0, acc[1][0]);
        acc[1][1] = MFMA_(af01, bc.b2, acc[1][1]);
        acc[0][0] = MFMA_(af10, bc.b1, acc[0][0]);
        acc[0][1] = MFMA_(af10, bc.b3, acc[0][1]);
        acc[1][0] = MFMA_(af11, bc.b1, acc[1][0]);
        acc[1][1] = MFMA_(af11, bc.b3, acc[1][1]);

        __syncthreads();
        cur ^= 1;
    };

    for (int g = 0; g < T; g += 2) {     // T is always even
        iter(g,     S0, S1, B0, B1);
        iter(g + 1, S1, S0, B1, B0);
    }

    // epilogue: C/D layout col = lane&15, row = (lane>>4)*4 + r  (verified)
    const int row0 = m0 + wr + (lane >> 4) * 4;
    const int col0 = o0 + wc + l15;
#pragma unroll
    for (int j = 0; j < 2; ++j) {
        const int cc = col0 + j * 16;
        if (cc < O) {
#pragma unroll
            for (int i = 0; i < 2; ++i)
#pragma unroll
                for (int r = 0; r < 4; ++r) {
                    const int row = row0 + i * 16 + r;
                    if constexpr (OUTMODE == 0)
                        ((float*)Cout)[(size_t)row * ldo + cc] = acc[i][j][r] + bias[cc];
                    else if constexpr (OUTMODE == 1)
                        ((unsigned short*)Cout)[(size_t)row * ldo + cc] =
                            f2bf(acc[i][j][r] + bias[cc]);
                    else
                        ((float*)Cout)[(size_t)zslab * (B_ * N_) * 64
                                       + (size_t)row * 64 + cc] = acc[i][j][r];
                }
        }
    }
}

// ---------------------------------------------------------------------------
// Weight fragment-packing, generic (used for small padded offset weights and
// KK==1 fc weights).  dst frag: ((o16*nk32+k32)*64 + (o&15)+((k>>3)&3)*16)*8+(k&7)
// ---------------------------------------------------------------------------
__global__ void pack_w(const float* __restrict__ w, unsigned short* __restrict__ dst,
                       int Ovalid, int Opad, int obase, int Kc, int KK, int t0, int Ktot)
{
    const int gid = blockIdx.x * blockDim.x + threadIdx.x;
    if (gid >= Opad * Ktot) return;
    const int k  = gid % Ktot;
    const int od = gid / Ktot;
    float v = 0.f;
    if (od < Ovalid) {
        const size_t o = obase + od;
        if (KK == 1) {
            v = w[o * Kc + k];
        } else {
            const int t = t0 + (k >> 9);
            const int c = k & 511;
            v = w[(o * Kc + c) * KK + t];
        }
    }
    const int o16 = od >> 4, l = od & 15, k32 = k >> 5;
    const size_t di = ((size_t)(o16 * (Ktot >> 5) + k32) * 64
                       + (l + ((k >> 3) & 3) * 16)) * 8 + (k & 7);
    dst[di] = f2bf(v);
}

// ---------------------------------------------------------------------------
// Conv weight packing, traffic-exact: thread per (o, c-pair), reads 2*KK
// CONTIGUOUS floats (no strided over-fetch), writes packed u32 (2 bf16).
// src w: [O][512][KK].  O multiple of 16.
// ---------------------------------------------------------------------------
__global__ void pack_conv(const float* __restrict__ w, unsigned short* __restrict__ dst,
                          int O, int KK)
{
    const int gid = blockIdx.x * blockDim.x + threadIdx.x;
    if (gid >= O * 256) return;
    const int c2 = gid & 255;
    const int o  = gid >> 8;
    const int c  = c2 << 1;
    const float* src = w + ((size_t)o * 512 + c) * KK;
    const int nk32 = KK << 4;
    const int o16 = o >> 4, l = o & 15;
    for (int t = 0; t < KK; ++t) {
        const float v0 = src[t];
        const float v1 = src[KK + t];
        const int k = t * 512 + c;
        const size_t di = ((size_t)(o16 * nk32 + (k >> 5)) * 64
                           + (l + ((k >> 3) & 3) * 16)) * 8 + (k & 7);
        *(unsigned int*)&dst[di] = f2bf2(v0, v1);
    }
}

// ---------------------------------------------------------------------------
// Bilinear coefficients; offsets arrive as Z K-split partial slabs + bias.
// offp: [Z][4096][64], dy at col 2t, dx at col 2t+1.  cidx stored short4.
// ---------------------------------------------------------------------------
template<int KS, int Z>
__global__ void coeff_kernel(const float* __restrict__ offp,
                             const float* __restrict__ ob,
                             short4* __restrict__ cidx, float4* __restrict__ cwt)
{
    const int KK = KS * KS, PAD = KS / 2;
    const int gid = blockIdx.x * blockDim.x + threadIdx.x;
    if (gid >= B_ * N_ * KK) return;
    const int t = gid % KK;
    const int n = (gid / KK) & (N_ - 1);
    const int b = gid / (KK * N_);
    const int mtok = b * N_ + n;

    const int SL = B_ * N_ * 64;
    float dy = ob[2 * t], dx = ob[2 * t + 1];
#pragma unroll
    for (int z = 0; z < Z; ++z) {
        dy += offp[(size_t)z * SL + (size_t)mtok * 64 + 2 * t];
        dx += offp[(size_t)z * SL + (size_t)mtok * 64 + 2 * t + 1];
    }

    const int y = n >> 5, x = n & 31;
    const float py = (float)(y - PAD + t / KS) + dy;
    const float px = (float)(x - PAD + t % KS) + dx;
    const float y0f = floorf(py), x0f = floorf(px);
    const float fy = py - y0f, fx = px - x0f;
    const int y0 = (int)y0f, x0 = (int)x0f;

    int idx[4]; float wt[4];
    const int   yy[4] = {y0, y0, y0 + 1, y0 + 1};
    const int   xx[4] = {x0, x0 + 1, x0, x0 + 1};
    const float ww[4] = {(1.f - fy) * (1.f - fx), (1.f - fy) * fx,
                         fy * (1.f - fx),         fy * fx};
#pragma unroll
    for (int r = 0; r < 4; ++r) {
        const bool v = (yy[r] >= 0 && yy[r] < H_ && xx[r] >= 0 && xx[r] < W_);
        const int yc = min(max(yy[r], 0), H_ - 1);
        const int xc = min(max(xx[r], 0), W_ - 1);
        idx[r] = b * N_ + yc * W_ + xc;
        wt[r] = v ? ww[r] : 0.f;
    }
    cidx[(size_t)mtok * KK + t] =
        make_short4((short)idx[0], (short)idx[1], (short)idx[2], (short)idx[3]);
    cwt[(size_t)mtok * KK + t] = make_float4(wt[0], wt[1], wt[2], wt[3]);
}

// ---------------------------------------------------------------------------
// LayerNorm + exact GELU  (verified)
// ---------------------------------------------------------------------------
__global__ __launch_bounds__(256)
void ln_gelu(float* __restrict__ ytok, const float* __restrict__ g,
             const float* __restrict__ bt)
{
    const int t = blockIdx.x;
    const int tid = threadIdx.x;
    float* row = ytok + (size_t)t * CHID_;

    float4 v = *(const float4*)&row[tid << 2];
    __shared__ float red[4];

    float s = v.x + v.y + v.z + v.w;
#pragma unroll
    for (int o = 32; o > 0; o >>= 1) s += __shfl_down(s, o, 64);
    if ((tid & 63) == 0) red[tid >> 6] = s;
    __syncthreads();
    const float mean = (red[0] + red[1] + red[2] + red[3]) * (1.f / CHID_);

    const float d0 = v.x - mean, d1 = v.y - mean, d2 = v.z - mean, d3 = v.w - mean;
    float q = d0 * d0 + d1 * d1 + d2 * d2 + d3 * d3;
#pragma unroll
    for (int o = 32; o > 0; o >>= 1) q += __shfl_down(q, o, 64);
    __syncthreads();
    if ((tid & 63) == 0) red[tid >> 6] = q;
    __syncthreads();
    const float var = (red[0] + red[1] + red[2] + red[3]) * (1.f / CHID_);
    const float rstd = rsqrtf(var + 1e-5f);

    const float4 gv = *(const float4*)&g[tid << 2];
    const float4 bv = *(const float4*)&bt[tid << 2];
    float o0 = d0 * rstd * gv.x + bv.x;
    float o1 = d1 * rstd * gv.y + bv.y;
    float o2 = d2 * rstd * gv.z + bv.z;
    float o3 = d3 * rstd * gv.w + bv.w;
    o0 = 0.5f * o0 * (1.f + erff(o0 * 0.70710678118654752f));
    o1 = 0.5f * o1 * (1.f + erff(o1 * 0.70710678118654752f));
    o2 = 0.5f * o2 * (1.f + erff(o2 * 0.70710678118654752f));
    o3 = 0.5f * o3 * (1.f + erff(o3 * 0.70710678118654752f));
    *(float4*)&row[tid << 2] = make_float4(o0, o1, o2, o3);
}

// ---------------------------------------------------------------------------
extern "C" void kernel_launch(void* const* d_in, const int* in_sizes, int n_in,
                              void* d_out, int out_size, void* d_ws, size_t ws_size,
                              hipStream_t stream) {
    const float* x       = (const float*)d_in[0];
    const float* fc1_w   = (const float*)d_in[3];
    const float* fc1_b   = (const float*)d_in[4];
    const float* off3_w  = (const float*)d_in[5];
    const float* off3_b  = (const float*)d_in[6];
    const float* conv3_w = (const float*)d_in[7];
    const float* conv3_b = (const float*)d_in[8];
    const float* off5_w  = (const float*)d_in[9];
    const float* off5_b  = (const float*)d_in[10];
    const float* conv5_w = (const float*)d_in[11];
    const float* conv5_b = (const float*)d_in[12];
    const float* ln_g    = (const float*)d_in[13];
    const float* ln_b    = (const float*)d_in[14];
    const float* fc2_w   = (const float*)d_in[15];
    const float* fc2_b   = (const float*)d_in[16];
    float* out = (float*)d_out;

    // Workspace (peak 50.17 MB <= 51.2 MB floor), liveness overlays as R5.
    char* ws = (char*)d_ws;
    float*          ytok   = (float*)(ws);                    // [4096][1024] fp32
    float*          offp   = (float*)(ws);                    // [<=5][4096][64]
    short4*         cidx3  = (short4*)(ws + 5242880);         //   294,912
    float4*         cwt3   = (float4*)(ws + 5537792);         //   589,824
    short4*         cidx5  = (short4*)(ws + 16777216);        //   819,200
    float4*         cwt5   = (float4*)(ws + 17596416);        // 1,638,400
    unsigned short* hb     = (unsigned short*)(ws + 19234816);// [4096][1024] bf16
    unsigned short* fc1wb  = (unsigned short*)(ws + 27623424);//   524,288
    unsigned short* off3wb = (unsigned short*)(ws + 28147712);//   589,824
    unsigned short* off5wb = (unsigned short*)(ws + 28737536);// 1,638,400
    unsigned short* daccb  = (unsigned short*)(ws + 27623424);// 4,194,304 (overlay)
    unsigned short* fc2wb  = (unsigned short*)(ws + 31817728);//   524,288
    unsigned short* conv3wb= (unsigned short*)(ws + 32342016);// 4,718,592
    unsigned short* conv5wb= (unsigned short*)(ws + 37060608);// 13,107,200 -> 50,167,808

    const dim3 TB(256);
    const dim3 TG(512);

    // ---- weight packs ----
    pack_w<<<(1024*256 + 255)/256, TB, 0, stream>>>(fc1_w, fc1wb, 1024, 1024, 0, 256, 1, 0, 256);
    pack_w<<<(256*1024 + 255)/256, TB, 0, stream>>>(fc2_w, fc2wb, 256, 256, 0, 1024, 1, 0, 1024);
    pack_w<<<(64*4608  + 255)/256, TB, 0, stream>>>(off3_w, off3wb, 18, 64, 0, 512, 9, 0, 4608);
    pack_w<<<(64*12800 + 255)/256, TB, 0, stream>>>(off5_w, off5wb, 50, 64, 0, 512, 25, 0, 12800);
    pack_conv<<<(512*256 + 255)/256, TB, 0, stream>>>(conv3_w, conv3wb, 512, 9);
    pack_conv<<<(512*256 + 255)/256, TB, 0, stream>>>(conv5_w, conv5wb, 512, 25);

    // ---- fc1: hb = bf16(x @ fc1_w^T + b) ----
    cgemm<0,1,4,1,8><<<8*64, TG, 0, stream>>>(
        x, CIN_, fc1wb, 8, 1, 1, fc1_b, hb, CHID_, CHID_, 64, nullptr, nullptr);

    // ---- offset convs (tap-split partials) + coeffs ----
    cgemm<1,3,8,2,0><<<dim3(1,64,3), TG, 0, stream>>>(
        hb, CHID_, off3wb, 144, 3, 1, nullptr, offp, 64, 18, 4, nullptr, nullptr);
    coeff_kernel<3,3><<<(B_*N_*9 + 255)/256, TB, 0, stream>>>(offp, off3_b, cidx3, cwt3);
    cgemm<1,5,8,2,0><<<dim3(1,64,5), TG, 0, stream>>>(
        hb + C2_, CHID_, off5wb, 400, 5, 1, nullptr, offp, 64, 50, 4, nullptr, nullptr);
    coeff_kernel<5,5><<<(B_*N_*25 + 255)/256, TB, 0, stream>>>(offp, off5_b, cidx5, cwt5);

    // ---- branch 1: deform conv3 -> daccb (bf16), plain conv3 -> ytok[:, :512] ----
    cgemm<2,3,8,1,4><<<4*64, TG, 0, stream>>>(
        hb, CHID_, conv3wb, 144, 9, 9, conv3_b, daccb, C2_, C2_, 32, cidx3, cwt3);
    cgemm<1,3,8,0,4><<<4*64, TG, 0, stream>>>(
        daccb, C2_, conv3wb, 144, 9, 1, conv3_b, ytok, CHID_, C2_, 32, nullptr, nullptr);

    // ---- branch 2: deform conv5 -> daccb (bf16), plain conv5 -> ytok[:, 512:] ----
    cgemm<2,5,8,1,4><<<4*64, TG, 0, stream>>>(
        hb + C2_, CHID_, conv5wb, 400, 25, 25, conv5_b, daccb, C2_, C2_, 32, cidx5, cwt5);
    cgemm<1,5,8,0,4><<<4*64, TG, 0, stream>>>(
        daccb, C2_, conv5wb, 400, 25, 1, conv5_b, ytok + C2_, CHID_, C2_, 32, nullptr, nullptr);

    // ---- LN + GELU, then fc2 -> fp32 out ----
    ln_gelu<<<B_*N_, TB, 0, stream>>>(ytok, ln_g, ln_b);
    cgemm<0,1,16,0,2><<<2*64, TG, 0, stream>>>(
        ytok, CHID_, fc2wb, 32, 1, 1, fc2_b, out, CIN_, CIN_, 16, nullptr, nullptr);
}

// Round 7
// 676.161 us; speedup vs baseline: 1.0345x; 1.0345x over previous
//
#include <hip/hip_runtime.h>

// Problem constants (fixed by setup_inputs)
#define B_    4
#define H_    32
#define W_    32
#define N_    1024      // H*W
#define CIN_  256
#define CHID_ 1024
#define C2_   512

typedef __attribute__((ext_vector_type(8))) short short8b;   // 8 bf16
typedef __attribute__((ext_vector_type(4))) float f32x4;     // MFMA acc

// fp32 -> bf16 (RNE)
__device__ __forceinline__ unsigned int f2bf2(float lo, float hi) {
    unsigned int ul = __float_as_uint(lo);
    unsigned int uh = __float_as_uint(hi);
    ul += 0x7fffu + ((ul >> 16) & 1u);
    uh += 0x7fffu + ((uh >> 16) & 1u);
    return (ul >> 16) | (uh & 0xffff0000u);
}
__device__ __forceinline__ unsigned short f2bf(float f) {
    unsigned int u = __float_as_uint(f);
    u += 0x7fffu + ((u >> 16) & 1u);
    return (unsigned short)(u >> 16);
}
// single-instruction packed f32x2 -> bf16x2 (RNE), lo -> bits[15:0]
__device__ __forceinline__ unsigned int cvtpk(float lo, float hi) {
    unsigned int r;
    asm("v_cvt_pk_bf16_f32 %0, %1, %2" : "=v"(r) : "v"(lo), "v"(hi));
    return r;
}
// bf16 pair -> f32 (bf16<<16 is the f32 bit pattern)
__device__ __forceinline__ float bflo(unsigned int u) { return __uint_as_float(u << 16); }
__device__ __forceinline__ float bfhi(unsigned int u) { return __uint_as_float(u & 0xffff0000u); }

#define ROWP 40   // LDS row pitch (ushorts): 80B stride -> 2-way alias = free
#define MFMA_(a, b, c) __builtin_amdgcn_mfma_f32_16x16x32_bf16(a, b, c, 0, 0, 0)

template<int X> struct Log2 { static constexpr int v = 1 + Log2<X/2>::v; };
template<> struct Log2<1> { static constexpr int v = 0; };

// Register staging sets (named fields only -> stays in VGPRs, rule #20)
struct ASet { uint4 r0, r1, r2, r3; float4 cw; };
struct BSet { short8b b0, b1, b2, b3; };

// ---------------------------------------------------------------------------
// bf16 MFMA GEMM, tile 64x128, 8 waves (2r x 4c), BK=64.
// 2-phase register pipeline (loads issued one step ahead of their blend).
// B fragment-packed in global, register double-buffered.
//   AMODE 0: fp32 row-major + cvt   (x for fc1, ytok for fc2); taps=1
//   AMODE 1: bf16 + spatial shift   (hb for offsets, daccb for plain convs)
//   AMODE 2: bf16 + bilinear gather (hb for deform convs)
//   OUTMODE 0: fp32 + bias   1: bf16 + bias   2: fp32 partial slab (z-split)
// Grid decode:
//   GX>0, IMGX=0: 1-D grid GX*64, o0=(bid&(GX-1))*128, m0=(bid/GX)*64
//   GX=4, IMGX=1: XCD-locality decode (grid must be 256, O=512):
//       b8=bid&7 (xcd), rest=bid>>3; img=b8>>1; og=((b8&1)<<1)|(rest&1);
//       mt=rest>>1.  Each XCD touches ONE image (1 MB A) + 2 o-groups
//       (3.3 MB B) -> L2-resident working set.
//   GX==0: (1, 64, Z): o0=0, taps z*tcnt..+tcnt, partial slab z.
// ---------------------------------------------------------------------------
template<int AMODE, int KS, int CH, int OUTMODE, int GX, int IMGX = 0>
__global__ __launch_bounds__(512, 2)
void cgemm(const void* __restrict__ Asrc, int lda,
           const unsigned short* __restrict__ Bp, int nk32,
           int tcnt, int KK,
           const float* __restrict__ bias, void* __restrict__ Cout,
           int ldo, int O, int nO16,
           const short4* __restrict__ cidx, const float4* __restrict__ cwt)
{
    constexpr int CHS = Log2<CH>::v;
    __shared__ unsigned short As[2][2][64 * ROWP];

    const int tid = threadIdx.x;
    int m0, o0, tbeg, zslab;
    if constexpr (GX > 0) {
        const int bid = blockIdx.x;
        if constexpr (IMGX) {
            const int b8 = bid & 7, rest = bid >> 3;
            o0 = ((((b8 & 1) << 1) | (rest & 1))) * 128;
            m0 = (((b8 >> 1) << 4) | (rest >> 1)) * 64;
        } else {
            o0 = (bid & (GX - 1)) * 128;
            m0 = (bid / GX) * 64;
        }
        tbeg = 0; zslab = 0;
    } else {
        o0 = 0;
        m0 = blockIdx.y * 64;
        zslab = blockIdx.z;
        tbeg = zslab * tcnt;
    }

    // staging role: row = tid>>3 (0..63), k-octet = (tid&7)*8
    const int srow = tid >> 3;
    const int sk8  = (tid & 7) << 3;
    const int am = m0 + srow;
    const int an = am & (N_ - 1), ab = am >> 10;
    const int ay = an >> 5, ax = an & 31;

    // compute role: 8 waves 2x4, wave subtile 32x32
    const int lane = tid & 63, wid = tid >> 6;
    const int wr = (wid >> 2) * 32, wc = (wid & 3) * 32;
    const int l15 = lane & 15, lk = (lane >> 4) * 8;

    const int o16a = min((o0 + wc) >> 4, nO16 - 1);
    const int o16b = min((o0 + wc + 16) >> 4, nO16 - 1);
    const unsigned short* bbA = Bp + (size_t)o16a * nk32 * 512 + lane * 8;
    const unsigned short* bbB = Bp + (size_t)o16b * nk32 * 512 + lane * 8;

    const int T = tcnt << CHS;          // total K64 steps
    const int qbase = (tbeg << CHS) * 2;

    // ---- load-side tap state ----
    const float* fp = nullptr;
    const unsigned short* sp = nullptr;
    bool svalid = false;
    const unsigned short *g0p = nullptr, *g1p = nullptr,
                         *g2p = nullptr, *g3p = nullptr;
    float4 curCw = {0.f, 0.f, 0.f, 0.f};
    short4 ciPref = {0, 0, 0, 0};
    float4 cwPref = {0.f, 0.f, 0.f, 0.f};

    if constexpr (AMODE == 0) {
        fp = (const float*)Asrc + (size_t)am * lda + sk8;
    } else if constexpr (AMODE == 2) {
        ciPref = cidx[(size_t)am * KK + tbeg];
        cwPref = cwt [(size_t)am * KK + tbeg];
    }

    auto advanceTap = [&](int tp) {
        if constexpr (AMODE == 1) {
            const int PAD = KS / 2;
            const int ty = tp / KS, tx = tp - ty * KS;
            const int yy = ay + ty - PAD, xx = ax + tx - PAD;
            svalid = (yy >= 0 && yy < H_ && xx >= 0 && xx < W_);
            if (svalid)
                sp = (const unsigned short*)Asrc
                   + (size_t)((ab << 10) | (yy << 5) | xx) * lda + sk8;
        } else if constexpr (AMODE == 2) {
            const unsigned short* base = (const unsigned short*)Asrc;
            g0p = base + (size_t)(int)ciPref.x * lda + sk8;
            g1p = base + (size_t)(int)ciPref.y * lda + sk8;
            g2p = base + (size_t)(int)ciPref.z * lda + sk8;
            g3p = base + (size_t)(int)ciPref.w * lda + sk8;
            curCw = cwPref;
            if (tp + 1 < tbeg + tcnt) {
                ciPref = cidx[(size_t)am * KK + tp + 1];   // prefetch next tap
                cwPref = cwt [(size_t)am * KK + tp + 1];
            }
        }
    };

    auto loadRaw = [&](ASet& S, int u) {
        if constexpr (AMODE == 0) {
            S.r0 = *(const uint4*)(fp + (u << 6));
            S.r1 = *(const uint4*)(fp + (u << 6) + 4);
        } else if constexpr (AMODE == 1) {
            S.r0 = svalid ? *(const uint4*)(sp + (u << 6))
                          : make_uint4(0u, 0u, 0u, 0u);
        } else {
            S.r0 = *(const uint4*)(g0p + (u << 6));
            S.r1 = *(const uint4*)(g1p + (u << 6));
            S.r2 = *(const uint4*)(g2p + (u << 6));
            S.r3 = *(const uint4*)(g3p + (u << 6));
            S.cw = curCw;
        }
    };

    auto bl1 = [](unsigned a, unsigned b, unsigned c, unsigned d, float4 cw) {
        const float lo = cw.x * bflo(a) + cw.y * bflo(b)
                       + cw.z * bflo(c) + cw.w * bflo(d);
        const float hi = cw.x * bfhi(a) + cw.y * bfhi(b)
                       + cw.z * bfhi(c) + cw.w * bfhi(d);
        return cvtpk(lo, hi);
    };

    auto blendWrite = [&](ASet& S, int buf) {
        uint4 o;
        if constexpr (AMODE == 0) {
            o = make_uint4(cvtpk(__uint_as_float(S.r0.x), __uint_as_float(S.r0.y)),
                           cvtpk(__uint_as_float(S.r0.z), __uint_as_float(S.r0.w)),
                           cvtpk(__uint_as_float(S.r1.x), __uint_as_float(S.r1.y)),
                           cvtpk(__uint_as_float(S.r1.z), __uint_as_float(S.r1.w)));
        } else if constexpr (AMODE == 1) {
            o = S.r0;
        } else {
            o = make_uint4(bl1(S.r0.x, S.r1.x, S.r2.x, S.r3.x, S.cw),
                           bl1(S.r0.y, S.r1.y, S.r2.y, S.r3.y, S.cw),
                           bl1(S.r0.z, S.r1.z, S.r2.z, S.r3.z, S.cw),
                           bl1(S.r0.w, S.r1.w, S.r2.w, S.r3.w, S.cw));
        }
        *(uint4*)&As[buf][sk8 >> 5][srow * ROWP + (sk8 & 31)] = o;
    };

    auto loadB = [&](BSet& Bv, int g) {
        const int q = qbase + 2 * g;
        Bv.b0 = *(const short8b*)(bbA + (size_t)q * 512);
        Bv.b1 = *(const short8b*)(bbA + (size_t)(q + 1) * 512);
        Bv.b2 = *(const short8b*)(bbB + (size_t)q * 512);
        Bv.b3 = *(const short8b*)(bbB + (size_t)(q + 1) * 512);
    };

    f32x4 acc[2][2];
#pragma unroll
    for (int i = 0; i < 2; ++i)
#pragma unroll
        for (int j = 0; j < 2; ++j)
            acc[i][j] = (f32x4){0.f, 0.f, 0.f, 0.f};

    ASet S0, S1; BSet B0, B1;

    // ---- prologue: stage step 0 into As[0]; raw-load step 1; B for step 0 ----
    advanceTap(tbeg);
    {
        ASet P;
        loadRaw(P, 0);
        blendWrite(P, 0);        // waits its own loads (one-time stall)
    }
    loadRaw(S0, 1);              // step 1 is within tap tbeg (CH >= 4)
    loadB(B0, 0);
    __syncthreads();

    int cur = 0;

    auto iter = [&](int g, ASet& N, ASet& F, BSet& bc, BSet& bn) {
        if (g + 1 < T) loadB(bn, g + 1);
        if (g + 2 < T) {
            const int gn = g + 2;
            if ((gn & (CH - 1)) == 0) advanceTap(tbeg + (gn >> CHS));
            loadRaw(F, gn & (CH - 1));
        }
        if (g + 1 < T) blendWrite(N, cur ^ 1);   // N loaded at step g-1

        const unsigned short* a0 = As[cur][0];
        const unsigned short* a1 = As[cur][1];
        const short8b af00 = *(const short8b*)(a0 + (wr      + l15) * ROWP + lk);
        const short8b af01 = *(const short8b*)(a0 + (wr + 16 + l15) * ROWP + lk);
        const short8b af10 = *(const short8b*)(a1 + (wr      + l15) * ROWP + lk);
        const short8b af11 = *(const short8b*)(a1 + (wr + 16 + l15) * ROWP + lk);

        acc[0][0] = MFMA_(af00, bc.b0, acc[0][0]);
        acc[0][1] = MFMA_(af00, bc.b2, acc[0][1]);
        acc[1][0] = MFMA_(af01, bc.b0, acc[1][0]);
        acc[1][1] = MFMA_(af01, bc.b2, acc[1][1]);
        acc[0][0] = MFMA_(af10, bc.b1, acc[0][0]);
        acc[0][1] = MFMA_(af10, bc.b3, acc[0][1]);
        acc[1][0] = MFMA_(af11, bc.b1, acc[1][0]);
        acc[1][1] = MFMA_(af11, bc.b3, acc[1][1]);

        __syncthreads();
        cur ^= 1;
    };

    for (int g = 0; g < T; g += 2) {     // T is always even
        iter(g,     S0, S1, B0, B1);
        iter(g + 1, S1, S0, B1, B0);
    }

    // epilogue: C/D layout col = lane&15, row = (lane>>4)*4 + r  (verified)
    const int row0 = m0 + wr + (lane >> 4) * 4;
    const int col0 = o0 + wc + l15;
#pragma unroll
    for (int j = 0; j < 2; ++j) {
        const int cc = col0 + j * 16;
        if (cc < O) {
#pragma unroll
            for (int i = 0; i < 2; ++i)
#pragma unroll
                for (int r = 0; r < 4; ++r) {
                    const int row = row0 + i * 16 + r;
                    if constexpr (OUTMODE == 0)
                        ((float*)Cout)[(size_t)row * ldo + cc] = acc[i][j][r] + bias[cc];
                    else if constexpr (OUTMODE == 1)
                        ((unsigned short*)Cout)[(size_t)row * ldo + cc] =
                            f2bf(acc[i][j][r] + bias[cc]);
                    else
                        ((float*)Cout)[(size_t)zslab * (B_ * N_) * 64
                                       + (size_t)row * 64 + cc] = acc[i][j][r];
                }
        }
    }
}

// ---------------------------------------------------------------------------
// Weight fragment-packing, generic (small padded offset weights, fc weights).
// dst frag: ((o16*nk32+k32)*64 + (o&15)+((k>>3)&3)*16)*8+(k&7)
// ---------------------------------------------------------------------------
__global__ void pack_w(const float* __restrict__ w, unsigned short* __restrict__ dst,
                       int Ovalid, int Opad, int obase, int Kc, int KK, int t0, int Ktot)
{
    const int gid = blockIdx.x * blockDim.x + threadIdx.x;
    if (gid >= Opad * Ktot) return;
    const int k  = gid % Ktot;
    const int od = gid / Ktot;
    float v = 0.f;
    if (od < Ovalid) {
        const size_t o = obase + od;
        if (KK == 1) {
            v = w[o * Kc + k];
        } else {
            const int t = t0 + (k >> 9);
            const int c = k & 511;
            v = w[(o * Kc + c) * KK + t];
        }
    }
    const int o16 = od >> 4, l = od & 15, k32 = k >> 5;
    const size_t di = ((size_t)(o16 * (Ktot >> 5) + k32) * 64
                       + (l + ((k >> 3) & 3) * 16)) * 8 + (k & 7);
    dst[di] = f2bf(v);
}

// ---------------------------------------------------------------------------
// Conv weight packing, traffic-exact: thread per (o, c-pair), reads 2*KK
// CONTIGUOUS floats, writes packed u32 (2 bf16).  src w: [O][512][KK].
// ---------------------------------------------------------------------------
__global__ void pack_conv(const float* __restrict__ w, unsigned short* __restrict__ dst,
                          int O, int KK)
{
    const int gid = blockIdx.x * blockDim.x + threadIdx.x;
    if (gid >= O * 256) return;
    const int c2 = gid & 255;
    const int o  = gid >> 8;
    const int c  = c2 << 1;
    const float* src = w + ((size_t)o * 512 + c) * KK;
    const int nk32 = KK << 4;
    const int o16 = o >> 4, l = o & 15;
    for (int t = 0; t < KK; ++t) {
        const float v0 = src[t];
        const float v1 = src[KK + t];
        const int k = t * 512 + c;
        const size_t di = ((size_t)(o16 * nk32 + (k >> 5)) * 64
                           + (l + ((k >> 3) & 3) * 16)) * 8 + (k & 7);
        *(unsigned int*)&dst[di] = f2bf2(v0, v1);
    }
}

// ---------------------------------------------------------------------------
// Bilinear coefficients; offsets arrive as Z K-split partial slabs + bias.
// offp: [Z][4096][64], dy at col 2t, dx at col 2t+1.  cidx stored short4.
// ---------------------------------------------------------------------------
template<int KS, int Z>
__global__ void coeff_kernel(const float* __restrict__ offp,
                             const float* __restrict__ ob,
                             short4* __restrict__ cidx, float4* __restrict__ cwt)
{
    const int KK = KS * KS, PAD = KS / 2;
    const int gid = blockIdx.x * blockDim.x + threadIdx.x;
    if (gid >= B_ * N_ * KK) return;
    const int t = gid % KK;
    const int n = (gid / KK) & (N_ - 1);
    const int b = gid / (KK * N_);
    const int mtok = b * N_ + n;

    const int SL = B_ * N_ * 64;
    float dy = ob[2 * t], dx = ob[2 * t + 1];
#pragma unroll
    for (int z = 0; z < Z; ++z) {
        dy += offp[(size_t)z * SL + (size_t)mtok * 64 + 2 * t];
        dx += offp[(size_t)z * SL + (size_t)mtok * 64 + 2 * t + 1];
    }

    const int y = n >> 5, x = n & 31;
    const float py = (float)(y - PAD + t / KS) + dy;
    const float px = (float)(x - PAD + t % KS) + dx;
    const float y0f = floorf(py), x0f = floorf(px);
    const float fy = py - y0f, fx = px - x0f;
    const int y0 = (int)y0f, x0 = (int)x0f;

    int idx[4]; float wt[4];
    const int   yy[4] = {y0, y0, y0 + 1, y0 + 1};
    const int   xx[4] = {x0, x0 + 1, x0, x0 + 1};
    const float ww[4] = {(1.f - fy) * (1.f - fx), (1.f - fy) * fx,
                         fy * (1.f - fx),         fy * fx};
#pragma unroll
    for (int r = 0; r < 4; ++r) {
        const bool v = (yy[r] >= 0 && yy[r] < H_ && xx[r] >= 0 && xx[r] < W_);
        const int yc = min(max(yy[r], 0), H_ - 1);
        const int xc = min(max(xx[r], 0), W_ - 1);
        idx[r] = b * N_ + yc * W_ + xc;
        wt[r] = v ? ww[r] : 0.f;
    }
    cidx[(size_t)mtok * KK + t] =
        make_short4((short)idx[0], (short)idx[1], (short)idx[2], (short)idx[3]);
    cwt[(size_t)mtok * KK + t] = make_float4(wt[0], wt[1], wt[2], wt[3]);
}

// ---------------------------------------------------------------------------
// LayerNorm + exact GELU  (verified)
// ---------------------------------------------------------------------------
__global__ __launch_bounds__(256)
void ln_gelu(float* __restrict__ ytok, const float* __restrict__ g,
             const float* __restrict__ bt)
{
    const int t = blockIdx.x;
    const int tid = threadIdx.x;
    float* row = ytok + (size_t)t * CHID_;

    float4 v = *(const float4*)&row[tid << 2];
    __shared__ float red[4];

    float s = v.x + v.y + v.z + v.w;
#pragma unroll
    for (int o = 32; o > 0; o >>= 1) s += __shfl_down(s, o, 64);
    if ((tid & 63) == 0) red[tid >> 6] = s;
    __syncthreads();
    const float mean = (red[0] + red[1] + red[2] + red[3]) * (1.f / CHID_);

    const float d0 = v.x - mean, d1 = v.y - mean, d2 = v.z - mean, d3 = v.w - mean;
    float q = d0 * d0 + d1 * d1 + d2 * d2 + d3 * d3;
#pragma unroll
    for (int o = 32; o > 0; o >>= 1) q += __shfl_down(q, o, 64);
    __syncthreads();
    if ((tid & 63) == 0) red[tid >> 6] = q;
    __syncthreads();
    const float var = (red[0] + red[1] + red[2] + red[3]) * (1.f / CHID_);
    const float rstd = rsqrtf(var + 1e-5f);

    const float4 gv = *(const float4*)&g[tid << 2];
    const float4 bv = *(const float4*)&bt[tid << 2];
    float o0 = d0 * rstd * gv.x + bv.x;
    float o1 = d1 * rstd * gv.y + bv.y;
    float o2 = d2 * rstd * gv.z + bv.z;
    float o3 = d3 * rstd * gv.w + bv.w;
    o0 = 0.5f * o0 * (1.f + erff(o0 * 0.70710678118654752f));
    o1 = 0.5f * o1 * (1.f + erff(o1 * 0.70710678118654752f));
    o2 = 0.5f * o2 * (1.f + erff(o2 * 0.70710678118654752f));
    o3 = 0.5f * o3 * (1.f + erff(o3 * 0.70710678118654752f));
    *(float4*)&row[tid << 2] = make_float4(o0, o1, o2, o3);
}

// ---------------------------------------------------------------------------
extern "C" void kernel_launch(void* const* d_in, const int* in_sizes, int n_in,
                              void* d_out, int out_size, void* d_ws, size_t ws_size,
                              hipStream_t stream) {
    const float* x       = (const float*)d_in[0];
    const float* fc1_w   = (const float*)d_in[3];
    const float* fc1_b   = (const float*)d_in[4];
    const float* off3_w  = (const float*)d_in[5];
    const float* off3_b  = (const float*)d_in[6];
    const float* conv3_w = (const float*)d_in[7];
    const float* conv3_b = (const float*)d_in[8];
    const float* off5_w  = (const float*)d_in[9];
    const float* off5_b  = (const float*)d_in[10];
    const float* conv5_w = (const float*)d_in[11];
    const float* conv5_b = (const float*)d_in[12];
    const float* ln_g    = (const float*)d_in[13];
    const float* ln_b    = (const float*)d_in[14];
    const float* fc2_w   = (const float*)d_in[15];
    const float* fc2_b   = (const float*)d_in[16];
    float* out = (float*)d_out;

    // Workspace (peak 50.17 MB <= 51.2 MB floor), liveness overlays as R5/R6.
    char* ws = (char*)d_ws;
    float*          ytok   = (float*)(ws);                    // [4096][1024] fp32
    float*          offp   = (float*)(ws);                    // [<=5][4096][64]
    short4*         cidx3  = (short4*)(ws + 5242880);         //   294,912
    float4*         cwt3   = (float4*)(ws + 5537792);         //   589,824
    short4*         cidx5  = (short4*)(ws + 16777216);        //   819,200
    float4*         cwt5   = (float4*)(ws + 17596416);        // 1,638,400
    unsigned short* hb     = (unsigned short*)(ws + 19234816);// [4096][1024] bf16
    unsigned short* fc1wb  = (unsigned short*)(ws + 27623424);//   524,288
    unsigned short* off3wb = (unsigned short*)(ws + 28147712);//   589,824
    unsigned short* off5wb = (unsigned short*)(ws + 28737536);// 1,638,400
    unsigned short* daccb  = (unsigned short*)(ws + 27623424);// 4,194,304 (overlay)
    unsigned short* fc2wb  = (unsigned short*)(ws + 31817728);//   524,288
    unsigned short* conv3wb= (unsigned short*)(ws + 32342016);// 4,718,592
    unsigned short* conv5wb= (unsigned short*)(ws + 37060608);// 13,107,200 -> 50,167,808

    const dim3 TB(256);
    const dim3 TG(512);

    // ---- weight packs ----
    pack_w<<<(1024*256 + 255)/256, TB, 0, stream>>>(fc1_w, fc1wb, 1024, 1024, 0, 256, 1, 0, 256);
    pack_w<<<(256*1024 + 255)/256, TB, 0, stream>>>(fc2_w, fc2wb, 256, 256, 0, 1024, 1, 0, 1024);
    pack_w<<<(64*4608  + 255)/256, TB, 0, stream>>>(off3_w, off3wb, 18, 64, 0, 512, 9, 0, 4608);
    pack_w<<<(64*12800 + 255)/256, TB, 0, stream>>>(off5_w, off5wb, 50, 64, 0, 512, 25, 0, 12800);
    pack_conv<<<(512*256 + 255)/256, TB, 0, stream>>>(conv3_w, conv3wb, 512, 9);
    pack_conv<<<(512*256 + 255)/256, TB, 0, stream>>>(conv5_w, conv5wb, 512, 25);

    // ---- fc1: hb = bf16(x @ fc1_w^T + b) ----
    cgemm<0,1,4,1,8><<<8*64, TG, 0, stream>>>(
        x, CIN_, fc1wb, 8, 1, 1, fc1_b, hb, CHID_, CHID_, 64, nullptr, nullptr);

    // ---- offset convs (tap-split partials) + coeffs ----
    cgemm<1,3,8,2,0><<<dim3(1,64,3), TG, 0, stream>>>(
        hb, CHID_, off3wb, 144, 3, 1, nullptr, offp, 64, 18, 4, nullptr, nullptr);
    coeff_kernel<3,3><<<(B_*N_*9 + 255)/256, TB, 0, stream>>>(offp, off3_b, cidx3, cwt3);
    cgemm<1,5,8,2,0><<<dim3(1,64,5), TG, 0, stream>>>(
        hb + C2_, CHID_, off5wb, 400, 5, 1, nullptr, offp, 64, 50, 4, nullptr, nullptr);
    coeff_kernel<5,5><<<(B_*N_*25 + 255)/256, TB, 0, stream>>>(offp, off5_b, cidx5, cwt5);

    // ---- branch 1: deform conv3 -> daccb (bf16), plain conv3 -> ytok[:, :512] ----
    cgemm<2,3,8,1,4,1><<<4*64, TG, 0, stream>>>(
        hb, CHID_, conv3wb, 144, 9, 9, conv3_b, daccb, C2_, C2_, 32, cidx3, cwt3);
    cgemm<1,3,8,0,4,1><<<4*64, TG, 0, stream>>>(
        daccb, C2_, conv3wb, 144, 9, 1, conv3_b, ytok, CHID_, C2_, 32, nullptr, nullptr);

    // ---- branch 2: deform conv5 -> daccb (bf16), plain conv5 -> ytok[:, 512:] ----
    cgemm<2,5,8,1,4,1><<<4*64, TG, 0, stream>>>(
        hb + C2_, CHID_, conv5wb, 400, 25, 25, conv5_b, daccb, C2_, C2_, 32, cidx5, cwt5);
    cgemm<1,5,8,0,4,1><<<4*64, TG, 0, stream>>>(
        daccb, C2_, conv5wb, 400, 25, 1, conv5_b, ytok + C2_, CHID_, C2_, 32, nullptr, nullptr);

    // ---- LN + GELU, then fc2 -> fp32 out ----
    ln_gelu<<<B_*N_, TB, 0, stream>>>(ytok, ln_g, ln_b);
    cgemm<0,1,16,0,2><<<2*64, TG, 0, stream>>>(
        ytok, CHID_, fc2wb, 32, 1, 1, fc2_b, out, CIN_, CIN_, 16, nullptr, nullptr);
}

// Round 8
// 600.060 us; speedup vs baseline: 1.1657x; 1.1268x over previous
//
#include <hip/hip_runtime.h>

// Problem constants (fixed by setup_inputs)
#define B_    4
#define H_    32
#define W_    32
#define N_    1024      // H*W
#define CIN_  256
#define CHID_ 1024
#define C2_   512

typedef __attribute__((ext_vector_type(8))) short short8b;   // 8 bf16
typedef __attribute__((ext_vector_type(4))) float f32x4;     // MFMA acc

// fp32 -> bf16 (RNE)
__device__ __forceinline__ unsigned int f2bf2(float lo, float hi) {
    unsigned int ul = __float_as_uint(lo);
    unsigned int uh = __float_as_uint(hi);
    ul += 0x7fffu + ((ul >> 16) & 1u);
    uh += 0x7fffu + ((uh >> 16) & 1u);
    return (ul >> 16) | (uh & 0xffff0000u);
}
__device__ __forceinline__ unsigned short f2bf(float f) {
    unsigned int u = __float_as_uint(f);
    u += 0x7fffu + ((u >> 16) & 1u);
    return (unsigned short)(u >> 16);
}
// single-instruction packed f32x2 -> bf16x2 (RNE), lo -> bits[15:0]
__device__ __forceinline__ unsigned int cvtpk(float lo, float hi) {
    unsigned int r;
    asm("v_cvt_pk_bf16_f32 %0, %1, %2" : "=v"(r) : "v"(lo), "v"(hi));
    return r;
}
// bf16 pair -> f32 (bf16<<16 is the f32 bit pattern)
__device__ __forceinline__ float bflo(unsigned int u) { return __uint_as_float(u << 16); }
__device__ __forceinline__ float bfhi(unsigned int u) { return __uint_as_float(u & 0xffff0000u); }

#define ROWP 40   // LDS row pitch (ushorts): 80B stride -> 2-way alias = free
#define MFMA_(a, b, c) __builtin_amdgcn_mfma_f32_16x16x32_bf16(a, b, c, 0, 0, 0)

template<int X> struct Log2 { static constexpr int v = 1 + Log2<X/2>::v; };
template<> struct Log2<1> { static constexpr int v = 0; };

// Register staging sets (named fields only -> stays in VGPRs, rule #20)
struct ASet { uint4 r0, r1, r2, r3; float4 cw; };
struct BSet { short8b b0, b1, b2, b3; };

// ---------------------------------------------------------------------------
// bf16 MFMA GEMM, tile MT x 128.  MT=64: 8 waves (2r x 4c), 512 thr.
// MT=32: 4 waves (1r x 4c), 256 thr -> grid doubles -> 2 blocks/CU, barriers
// decoupled across co-resident blocks (R7 fix for lockstep latency exposure).
// 2-phase register pipeline (A loads issued one step ahead of their blend).
// B fragment-packed in global, register double-buffered.
//   AMODE 0: fp32 row-major + cvt   (x for fc1, ytok for fc2); taps=1
//   AMODE 1: bf16 + spatial shift   (hb for offsets, daccb for plain convs)
//   AMODE 2: bf16 + bilinear gather (hb for deform convs)
//   OUTMODE 0: fp32 + bias   1: bf16 + bias   2: fp32 partial slab (z-split)
// Grid decode:
//   GX>0, IMGX=0: 1-D grid GX*(4096/MT), o0=(bid&(GX-1))*128, m0=(bid/GX)*MT
//   GX=4, IMGX=1: XCD-locality decode (O=512): b8=bid&7 -> img=b8>>1,
//       og=((b8&1)<<1)|(rest&1); each XCD touches ONE image + 2 o-groups
//       -> L2-resident. MT64: grid 256; MT32: grid 512.
//   GX==0: (1, 4096/MT, Z): o0=0, taps z*tcnt..+tcnt, partial slab z.
// ---------------------------------------------------------------------------
template<int AMODE, int KS, int CH, int OUTMODE, int GX, int IMGX = 0, int MT = 64>
__global__ __launch_bounds__((MT == 64) ? 512 : 256, (MT == 64) ? 2 : 4)
void cgemm(const void* __restrict__ Asrc, int lda,
           const unsigned short* __restrict__ Bp, int nk32,
           int tcnt, int KK,
           const float* __restrict__ bias, void* __restrict__ Cout,
           int ldo, int O, int nO16,
           const short4* __restrict__ cidx, const float4* __restrict__ cwt)
{
    constexpr int CHS = Log2<CH>::v;
    __shared__ unsigned short As[2][2][MT * ROWP];

    const int tid = threadIdx.x;
    int m0, o0, tbeg, zslab;
    if constexpr (GX > 0) {
        const int bid = blockIdx.x;
        if constexpr (IMGX) {
            const int b8 = bid & 7, rest = bid >> 3;
            o0 = (((b8 & 1) << 1) | (rest & 1)) * 128;
            if constexpr (MT == 64)
                m0 = (((b8 >> 1) << 4) | (rest >> 1)) * 64;
            else
                m0 = (b8 >> 1) * 1024 + (rest >> 1) * 32;
        } else {
            o0 = (bid & (GX - 1)) * 128;
            m0 = (bid / GX) * MT;
        }
        tbeg = 0; zslab = 0;
    } else {
        o0 = 0;
        m0 = blockIdx.y * MT;
        zslab = blockIdx.z;
        tbeg = zslab * tcnt;
    }

    // staging role: row = tid>>3, k-octet = (tid&7)*8  (covers MT rows exactly)
    const int srow = tid >> 3;
    const int sk8  = (tid & 7) << 3;
    const int am = m0 + srow;
    const int an = am & (N_ - 1), ab = am >> 10;
    const int ay = an >> 5, ax = an & 31;

    // compute role: waves tile (MT/32) x 4; wave subtile 32x32
    const int lane = tid & 63, wid = tid >> 6;
    int wr, wc;
    if constexpr (MT == 64) { wr = (wid >> 2) * 32; wc = (wid & 3) * 32; }
    else                    { wr = 0;               wc = wid * 32; }
    const int l15 = lane & 15, lk = (lane >> 4) * 8;

    const int o16a = min((o0 + wc) >> 4, nO16 - 1);
    const int o16b = min((o0 + wc + 16) >> 4, nO16 - 1);
    const unsigned short* bbA = Bp + (size_t)o16a * nk32 * 512 + lane * 8;
    const unsigned short* bbB = Bp + (size_t)o16b * nk32 * 512 + lane * 8;

    const int T = tcnt << CHS;          // total K64 steps
    const int qbase = (tbeg << CHS) * 2;

    // ---- load-side tap state ----
    const float* fp = nullptr;
    const unsigned short* sp = nullptr;
    bool svalid = false;
    const unsigned short *g0p = nullptr, *g1p = nullptr,
                         *g2p = nullptr, *g3p = nullptr;
    float4 curCw = {0.f, 0.f, 0.f, 0.f};
    short4 ciPref = {0, 0, 0, 0};
    float4 cwPref = {0.f, 0.f, 0.f, 0.f};

    if constexpr (AMODE == 0) {
        fp = (const float*)Asrc + (size_t)am * lda + sk8;
    } else if constexpr (AMODE == 2) {
        ciPref = cidx[(size_t)am * KK + tbeg];
        cwPref = cwt [(size_t)am * KK + tbeg];
    }

    auto advanceTap = [&](int tp) {
        if constexpr (AMODE == 1) {
            const int PAD = KS / 2;
            const int ty = tp / KS, tx = tp - ty * KS;
            const int yy = ay + ty - PAD, xx = ax + tx - PAD;
            svalid = (yy >= 0 && yy < H_ && xx >= 0 && xx < W_);
            if (svalid)
                sp = (const unsigned short*)Asrc
                   + (size_t)((ab << 10) | (yy << 5) | xx) * lda + sk8;
        } else if constexpr (AMODE == 2) {
            const unsigned short* base = (const unsigned short*)Asrc;
            g0p = base + (size_t)(int)ciPref.x * lda + sk8;
            g1p = base + (size_t)(int)ciPref.y * lda + sk8;
            g2p = base + (size_t)(int)ciPref.z * lda + sk8;
            g3p = base + (size_t)(int)ciPref.w * lda + sk8;
            curCw = cwPref;
            if (tp + 1 < tbeg + tcnt) {
                ciPref = cidx[(size_t)am * KK + tp + 1];   // prefetch next tap
                cwPref = cwt [(size_t)am * KK + tp + 1];
            }
        }
    };

    auto loadRaw = [&](ASet& S, int u) {
        if constexpr (AMODE == 0) {
            S.r0 = *(const uint4*)(fp + (u << 6));
            S.r1 = *(const uint4*)(fp + (u << 6) + 4);
        } else if constexpr (AMODE == 1) {
            S.r0 = svalid ? *(const uint4*)(sp + (u << 6))
                          : make_uint4(0u, 0u, 0u, 0u);
        } else {
            S.r0 = *(const uint4*)(g0p + (u << 6));
            S.r1 = *(const uint4*)(g1p + (u << 6));
            S.r2 = *(const uint4*)(g2p + (u << 6));
            S.r3 = *(const uint4*)(g3p + (u << 6));
            S.cw = curCw;
        }
    };

    auto bl1 = [](unsigned a, unsigned b, unsigned c, unsigned d, float4 cw) {
        const float lo = cw.x * bflo(a) + cw.y * bflo(b)
                       + cw.z * bflo(c) + cw.w * bflo(d);
        const float hi = cw.x * bfhi(a) + cw.y * bfhi(b)
                       + cw.z * bfhi(c) + cw.w * bfhi(d);
        return cvtpk(lo, hi);
    };

    auto blendWrite = [&](ASet& S, int buf) {
        uint4 o;
        if constexpr (AMODE == 0) {
            o = make_uint4(cvtpk(__uint_as_float(S.r0.x), __uint_as_float(S.r0.y)),
                           cvtpk(__uint_as_float(S.r0.z), __uint_as_float(S.r0.w)),
                           cvtpk(__uint_as_float(S.r1.x), __uint_as_float(S.r1.y)),
                           cvtpk(__uint_as_float(S.r1.z), __uint_as_float(S.r1.w)));
        } else if constexpr (AMODE == 1) {
            o = S.r0;
        } else {
            o = make_uint4(bl1(S.r0.x, S.r1.x, S.r2.x, S.r3.x, S.cw),
                           bl1(S.r0.y, S.r1.y, S.r2.y, S.r3.y, S.cw),
                           bl1(S.r0.z, S.r1.z, S.r2.z, S.r3.z, S.cw),
                           bl1(S.r0.w, S.r1.w, S.r2.w, S.r3.w, S.cw));
        }
        *(uint4*)&As[buf][sk8 >> 5][srow * ROWP + (sk8 & 31)] = o;
    };

    auto loadB = [&](BSet& Bv, int g) {
        const int q = qbase + 2 * g;
        Bv.b0 = *(const short8b*)(bbA + (size_t)q * 512);
        Bv.b1 = *(const short8b*)(bbA + (size_t)(q + 1) * 512);
        Bv.b2 = *(const short8b*)(bbB + (size_t)q * 512);
        Bv.b3 = *(const short8b*)(bbB + (size_t)(q + 1) * 512);
    };

    f32x4 acc[2][2];
#pragma unroll
    for (int i = 0; i < 2; ++i)
#pragma unroll
        for (int j = 0; j < 2; ++j)
            acc[i][j] = (f32x4){0.f, 0.f, 0.f, 0.f};

    ASet S0, S1; BSet B0, B1;

    // ---- prologue: stage step 0 into As[0]; raw-load step 1; B for step 0 ----
    advanceTap(tbeg);
    {
        ASet P;
        loadRaw(P, 0);
        blendWrite(P, 0);        // waits its own loads (one-time stall)
    }
    loadRaw(S0, 1);              // step 1 is within tap tbeg (CH >= 4)
    loadB(B0, 0);
    __syncthreads();

    int cur = 0;

    auto iter = [&](int g, ASet& N, ASet& F, BSet& bc, BSet& bn) {
        if (g + 1 < T) loadB(bn, g + 1);
        if (g + 2 < T) {
            const int gn = g + 2;
            if ((gn & (CH - 1)) == 0) advanceTap(tbeg + (gn >> CHS));
            loadRaw(F, gn & (CH - 1));
        }
        if (g + 1 < T) blendWrite(N, cur ^ 1);   // N loaded at step g-1

        const unsigned short* a0 = As[cur][0];
        const unsigned short* a1 = As[cur][1];
        const short8b af00 = *(const short8b*)(a0 + (wr      + l15) * ROWP + lk);
        const short8b af01 = *(const short8b*)(a0 + (wr + 16 + l15) * ROWP + lk);
        const short8b af10 = *(const short8b*)(a1 + (wr      + l15) * ROWP + lk);
        const short8b af11 = *(const short8b*)(a1 + (wr + 16 + l15) * ROWP + lk);

        acc[0][0] = MFMA_(af00, bc.b0, acc[0][0]);
        acc[0][1] = MFMA_(af00, bc.b2, acc[0][1]);
        acc[1][0] = MFMA_(af01, bc.b0, acc[1][0]);
        acc[1][1] = MFMA_(af01, bc.b2, acc[1][1]);
        acc[0][0] = MFMA_(af10, bc.b1, acc[0][0]);
        acc[0][1] = MFMA_(af10, bc.b3, acc[0][1]);
        acc[1][0] = MFMA_(af11, bc.b1, acc[1][0]);
        acc[1][1] = MFMA_(af11, bc.b3, acc[1][1]);

        __syncthreads();
        cur ^= 1;
    };

    for (int g = 0; g < T; g += 2) {     // T is always even
        iter(g,     S0, S1, B0, B1);
        iter(g + 1, S1, S0, B1, B0);
    }

    // epilogue: C/D layout col = lane&15, row = (lane>>4)*4 + r  (verified)
    const int row0 = m0 + wr + (lane >> 4) * 4;
    const int col0 = o0 + wc + l15;
#pragma unroll
    for (int j = 0; j < 2; ++j) {
        const int cc = col0 + j * 16;
        if (cc < O) {
#pragma unroll
            for (int i = 0; i < 2; ++i)
#pragma unroll
                for (int r = 0; r < 4; ++r) {
                    const int row = row0 + i * 16 + r;
                    if constexpr (OUTMODE == 0)
                        ((float*)Cout)[(size_t)row * ldo + cc] = acc[i][j][r] + bias[cc];
                    else if constexpr (OUTMODE == 1)
                        ((unsigned short*)Cout)[(size_t)row * ldo + cc] =
                            f2bf(acc[i][j][r] + bias[cc]);
                    else
                        ((float*)Cout)[(size_t)zslab * (B_ * N_) * 64
                                       + (size_t)row * 64 + cc] = acc[i][j][r];
                }
        }
    }
}

// ---------------------------------------------------------------------------
// Weight fragment-packing, generic (small padded offset weights, fc weights).
// dst frag: ((o16*nk32+k32)*64 + (o&15)+((k>>3)&3)*16)*8+(k&7)
// ---------------------------------------------------------------------------
__global__ void pack_w(const float* __restrict__ w, unsigned short* __restrict__ dst,
                       int Ovalid, int Opad, int obase, int Kc, int KK, int t0, int Ktot)
{
    const int gid = blockIdx.x * blockDim.x + threadIdx.x;
    if (gid >= Opad * Ktot) return;
    const int k  = gid % Ktot;
    const int od = gid / Ktot;
    float v = 0.f;
    if (od < Ovalid) {
        const size_t o = obase + od;
        if (KK == 1) {
            v = w[o * Kc + k];
        } else {
            const int t = t0 + (k >> 9);
            const int c = k & 511;
            v = w[(o * Kc + c) * KK + t];
        }
    }
    const int o16 = od >> 4, l = od & 15, k32 = k >> 5;
    const size_t di = ((size_t)(o16 * (Ktot >> 5) + k32) * 64
                       + (l + ((k >> 3) & 3) * 16)) * 8 + (k & 7);
    dst[di] = f2bf(v);
}

// ---------------------------------------------------------------------------
// Conv weight packing, traffic-exact: thread per (o, c-pair), reads 2*KK
// CONTIGUOUS floats, writes packed u32 (2 bf16).  src w: [O][512][KK].
// ---------------------------------------------------------------------------
__global__ void pack_conv(const float* __restrict__ w, unsigned short* __restrict__ dst,
                          int O, int KK)
{
    const int gid = blockIdx.x * blockDim.x + threadIdx.x;
    if (gid >= O * 256) return;
    const int c2 = gid & 255;
    const int o  = gid >> 8;
    const int c  = c2 << 1;
    const float* src = w + ((size_t)o * 512 + c) * KK;
    const int nk32 = KK << 4;
    const int o16 = o >> 4, l = o & 15;
    for (int t = 0; t < KK; ++t) {
        const float v0 = src[t];
        const float v1 = src[KK + t];
        const int k = t * 512 + c;
        const size_t di = ((size_t)(o16 * nk32 + (k >> 5)) * 64
                           + (l + ((k >> 3) & 3) * 16)) * 8 + (k & 7);
        *(unsigned int*)&dst[di] = f2bf2(v0, v1);
    }
}

// ---------------------------------------------------------------------------
// Bilinear coefficients; offsets arrive as Z K-split partial slabs + bias.
// offp: [Z][4096][64], dy at col 2t, dx at col 2t+1.  cidx stored short4.
// ---------------------------------------------------------------------------
template<int KS, int Z>
__global__ void coeff_kernel(const float* __restrict__ offp,
                             const float* __restrict__ ob,
                             short4* __restrict__ cidx, float4* __restrict__ cwt)
{
    const int KK = KS * KS, PAD = KS / 2;
    const int gid = blockIdx.x * blockDim.x + threadIdx.x;
    if (gid >= B_ * N_ * KK) return;
    const int t = gid % KK;
    const int n = (gid / KK) & (N_ - 1);
    const int b = gid / (KK * N_);
    const int mtok = b * N_ + n;

    const int SL = B_ * N_ * 64;
    float dy = ob[2 * t], dx = ob[2 * t + 1];
#pragma unroll
    for (int z = 0; z < Z; ++z) {
        dy += offp[(size_t)z * SL + (size_t)mtok * 64 + 2 * t];
        dx += offp[(size_t)z * SL + (size_t)mtok * 64 + 2 * t + 1];
    }

    const int y = n >> 5, x = n & 31;
    const float py = (float)(y - PAD + t / KS) + dy;
    const float px = (float)(x - PAD + t % KS) + dx;
    const float y0f = floorf(py), x0f = floorf(px);
    const float fy = py - y0f, fx = px - x0f;
    const int y0 = (int)y0f, x0 = (int)x0f;

    int idx[4]; float wt[4];
    const int   yy[4] = {y0, y0, y0 + 1, y0 + 1};
    const int   xx[4] = {x0, x0 + 1, x0, x0 + 1};
    const float ww[4] = {(1.f - fy) * (1.f - fx), (1.f - fy) * fx,
                         fy * (1.f - fx),         fy * fx};
#pragma unroll
    for (int r = 0; r < 4; ++r) {
        const bool v = (yy[r] >= 0 && yy[r] < H_ && xx[r] >= 0 && xx[r] < W_);
        const int yc = min(max(yy[r], 0), H_ - 1);
        const int xc = min(max(xx[r], 0), W_ - 1);
        idx[r] = b * N_ + yc * W_ + xc;
        wt[r] = v ? ww[r] : 0.f;
    }
    cidx[(size_t)mtok * KK + t] =
        make_short4((short)idx[0], (short)idx[1], (short)idx[2], (short)idx[3]);
    cwt[(size_t)mtok * KK + t] = make_float4(wt[0], wt[1], wt[2], wt[3]);
}

// ---------------------------------------------------------------------------
// LayerNorm + exact GELU  (verified)
// ---------------------------------------------------------------------------
__global__ __launch_bounds__(256)
void ln_gelu(float* __restrict__ ytok, const float* __restrict__ g,
             const float* __restrict__ bt)
{
    const int t = blockIdx.x;
    const int tid = threadIdx.x;
    float* row = ytok + (size_t)t * CHID_;

    float4 v = *(const float4*)&row[tid << 2];
    __shared__ float red[4];

    float s = v.x + v.y + v.z + v.w;
#pragma unroll
    for (int o = 32; o > 0; o >>= 1) s += __shfl_down(s, o, 64);
    if ((tid & 63) == 0) red[tid >> 6] = s;
    __syncthreads();
    const float mean = (red[0] + red[1] + red[2] + red[3]) * (1.f / CHID_);

    const float d0 = v.x - mean, d1 = v.y - mean, d2 = v.z - mean, d3 = v.w - mean;
    float q = d0 * d0 + d1 * d1 + d2 * d2 + d3 * d3;
#pragma unroll
    for (int o = 32; o > 0; o >>= 1) q += __shfl_down(q, o, 64);
    __syncthreads();
    if ((tid & 63) == 0) red[tid >> 6] = q;
    __syncthreads();
    const float var = (red[0] + red[1] + red[2] + red[3]) * (1.f / CHID_);
    const float rstd = rsqrtf(var + 1e-5f);

    const float4 gv = *(const float4*)&g[tid << 2];
    const float4 bv = *(const float4*)&bt[tid << 2];
    float o0 = d0 * rstd * gv.x + bv.x;
    float o1 = d1 * rstd * gv.y + bv.y;
    float o2 = d2 * rstd * gv.z + bv.z;
    float o3 = d3 * rstd * gv.w + bv.w;
    o0 = 0.5f * o0 * (1.f + erff(o0 * 0.70710678118654752f));
    o1 = 0.5f * o1 * (1.f + erff(o1 * 0.70710678118654752f));
    o2 = 0.5f * o2 * (1.f + erff(o2 * 0.70710678118654752f));
    o3 = 0.5f * o3 * (1.f + erff(o3 * 0.70710678118654752f));
    *(float4*)&row[tid << 2] = make_float4(o0, o1, o2, o3);
}

// ---------------------------------------------------------------------------
extern "C" void kernel_launch(void* const* d_in, const int* in_sizes, int n_in,
                              void* d_out, int out_size, void* d_ws, size_t ws_size,
                              hipStream_t stream) {
    const float* x       = (const float*)d_in[0];
    const float* fc1_w   = (const float*)d_in[3];
    const float* fc1_b   = (const float*)d_in[4];
    const float* off3_w  = (const float*)d_in[5];
    const float* off3_b  = (const float*)d_in[6];
    const float* conv3_w = (const float*)d_in[7];
    const float* conv3_b = (const float*)d_in[8];
    const float* off5_w  = (const float*)d_in[9];
    const float* off5_b  = (const float*)d_in[10];
    const float* conv5_w = (const float*)d_in[11];
    const float* conv5_b = (const float*)d_in[12];
    const float* ln_g    = (const float*)d_in[13];
    const float* ln_b    = (const float*)d_in[14];
    const float* fc2_w   = (const float*)d_in[15];
    const float* fc2_b   = (const float*)d_in[16];
    float* out = (float*)d_out;

    // Workspace (peak 50.17 MB <= 51.2 MB floor), liveness overlays as R5-R7.
    char* ws = (char*)d_ws;
    float*          ytok   = (float*)(ws);                    // [4096][1024] fp32
    float*          offp   = (float*)(ws);                    // [<=5][4096][64]
    short4*         cidx3  = (short4*)(ws + 5242880);         //   294,912
    float4*         cwt3   = (float4*)(ws + 5537792);         //   589,824
    short4*         cidx5  = (short4*)(ws + 16777216);        //   819,200
    float4*         cwt5   = (float4*)(ws + 17596416);        // 1,638,400
    unsigned short* hb     = (unsigned short*)(ws + 19234816);// [4096][1024] bf16
    unsigned short* fc1wb  = (unsigned short*)(ws + 27623424);//   524,288
    unsigned short* off3wb = (unsigned short*)(ws + 28147712);//   589,824
    unsigned short* off5wb = (unsigned short*)(ws + 28737536);// 1,638,400
    unsigned short* daccb  = (unsigned short*)(ws + 27623424);// 4,194,304 (overlay)
    unsigned short* fc2wb  = (unsigned short*)(ws + 31817728);//   524,288
    unsigned short* conv3wb= (unsigned short*)(ws + 32342016);// 4,718,592
    unsigned short* conv5wb= (unsigned short*)(ws + 37060608);// 13,107,200 -> 50,167,808

    const dim3 TB(256);
    const dim3 TG(512);
    const dim3 TG4(256);

    // ---- weight packs ----
    pack_w<<<(1024*256 + 255)/256, TB, 0, stream>>>(fc1_w, fc1wb, 1024, 1024, 0, 256, 1, 0, 256);
    pack_w<<<(256*1024 + 255)/256, TB, 0, stream>>>(fc2_w, fc2wb, 256, 256, 0, 1024, 1, 0, 1024);
    pack_w<<<(64*4608  + 255)/256, TB, 0, stream>>>(off3_w, off3wb, 18, 64, 0, 512, 9, 0, 4608);
    pack_w<<<(64*12800 + 255)/256, TB, 0, stream>>>(off5_w, off5wb, 50, 64, 0, 512, 25, 0, 12800);
    pack_conv<<<(512*256 + 255)/256, TB, 0, stream>>>(conv3_w, conv3wb, 512, 9);
    pack_conv<<<(512*256 + 255)/256, TB, 0, stream>>>(conv5_w, conv5wb, 512, 25);

    // ---- fc1: hb = bf16(x @ fc1_w^T + b)  (MT64, grid 512 = 2/CU already) ----
    cgemm<0,1,4,1,8><<<8*64, TG, 0, stream>>>(
        x, CIN_, fc1wb, 8, 1, 1, fc1_b, hb, CHID_, CHID_, 64, nullptr, nullptr);

    // ---- offset convs (tap-split partials, MT32) + coeffs ----
    cgemm<1,3,8,2,0,0,32><<<dim3(1,128,3), TG4, 0, stream>>>(
        hb, CHID_, off3wb, 144, 3, 1, nullptr, offp, 64, 18, 4, nullptr, nullptr);
    coeff_kernel<3,3><<<(B_*N_*9 + 255)/256, TB, 0, stream>>>(offp, off3_b, cidx3, cwt3);
    cgemm<1,5,8,2,0,0,32><<<dim3(1,128,5), TG4, 0, stream>>>(
        hb + C2_, CHID_, off5wb, 400, 5, 1, nullptr, offp, 64, 50, 4, nullptr, nullptr);
    coeff_kernel<5,5><<<(B_*N_*25 + 255)/256, TB, 0, stream>>>(offp, off5_b, cidx5, cwt5);

    // ---- branch 1 (MT32, grid 512 = 2/CU, XCD-local) ----
    cgemm<2,3,8,1,4,1,32><<<512, TG4, 0, stream>>>(
        hb, CHID_, conv3wb, 144, 9, 9, conv3_b, daccb, C2_, C2_, 32, cidx3, cwt3);
    cgemm<1,3,8,0,4,1,32><<<512, TG4, 0, stream>>>(
        daccb, C2_, conv3wb, 144, 9, 1, conv3_b, ytok, CHID_, C2_, 32, nullptr, nullptr);

    // ---- branch 2 (MT32) ----
    cgemm<2,5,8,1,4,1,32><<<512, TG4, 0, stream>>>(
        hb + C2_, CHID_, conv5wb, 400, 25, 25, conv5_b, daccb, C2_, C2_, 32, cidx5, cwt5);
    cgemm<1,5,8,0,4,1,32><<<512, TG4, 0, stream>>>(
        daccb, C2_, conv5wb, 400, 25, 1, conv5_b, ytok + C2_, CHID_, C2_, 32, nullptr, nullptr);

    // ---- LN + GELU, then fc2 -> fp32 out (MT32, grid 256) ----
    ln_gelu<<<B_*N_, TB, 0, stream>>>(ytok, ln_g, ln_b);
    cgemm<0,1,16,0,2,0,32><<<2*128, TG4, 0, stream>>>(
        ytok, CHID_, fc2wb, 32, 1, 1, fc2_b, out, CIN_, CIN_, 16, nullptr, nullptr);
}